// Round 7
// baseline (426.988 us; speedup 1.0000x reference)
//
#include <hip/hip_runtime.h>
#include <hip/hip_bf16.h>

// MLPDecoder: scores[e] = relu((h[src]*h[dst]) @ W1 + b1) @ W2 + b2
// E=300000, D=256. bf16 MFMA, 1-barrier/iter pipeline.
// R1: latency theory (Occ 34.5%) -> grid bump: NEUTRAL.
// R2 FAILED: lb(512,8) clamped VGPR->32, spilled (WRITE 142MB, 241us).
// R3 NEUTRAL: GRID=1024+lb(512,4): 78us. Occupancy is NOT the lever.
// R4 NEUTRAL: no-vmcnt-drain barrier + MFMA-first order: 77us.
// R5 FAILED: 64-col waves with lb(256,4) -> VGPR clamp -> spill, 207us.
// R6 WIN: 64-col waves + lb(256,2): 64.2us (was 77.7). VGPR 120 (no
// spill), MfmaUtil 25%. LDS-traffic theory directionally confirmed.
// SQ_LDS_BANK_CONFLICT == 6.000M in EVERY round (structure-invariant) ->
// tracks had-ds_writes, which still hit the 8-cy b128 floor; not a lever.
// R7 (THIS ROUND): ABLATION. Per-tile-pair model: LDS ~3200cy, VALU
// ~2400cy, MFMA ~620cy vs 8400 measured — attribution unproven after 2
// neutral schedule rounds. V0 unchanged (real out). decoder_v1 =
// staging-only x3 passes (MFMA+epilogue behind runtime-false `keep` to
// preserve reg pressure). decoder_v2 = staging+MFMA x2 passes (acc kept
// via asm sink; epilogue guarded). Readout: S=v1/3, S+M=v2/2, E=64-v2/2.
// Bench dur will be ~400us this round by design (diagnostic).

#define E_EDGES 300000
#define DIM 256
#define MT 32                    // edges per block-iteration
#define NTILES (E_EDGES / MT)    // 9375
#define BLK 256                  // 4 waves; each wave owns 64 N-cols
#define GRID_MAIN 512            // 2 blocks/CU
#define MAXJ 19                  // ceil(9375/512)

typedef short bf16x8 __attribute__((ext_vector_type(8)));
typedef float f32x4 __attribute__((ext_vector_type(4)));

__device__ __forceinline__ ushort f2bf(float f) {
    union { float f; unsigned u; } v; v.f = f;
    unsigned r = v.u + 0x7FFFu + ((v.u >> 16) & 1u);  // RNE
    return (ushort)(r >> 16);
}

// Barrier that does NOT drain vmcnt (LDS producers covered by lgkmcnt(0)).
__device__ __forceinline__ void barrier_lgkm() {
    asm volatile("s_waitcnt lgkmcnt(0)" ::: "memory");
    asm volatile("s_barrier" ::: "memory");
}

// W1 fp32 [K=256][N=256] -> W1^T bf16 [N][K]
__global__ void prep_w1t(const float* __restrict__ w1, ushort* __restrict__ w1t) {
    int idx = blockIdx.x * 256 + threadIdx.x;
    int k = idx >> 8, n = idx & 255;
    w1t[n * 256 + k] = f2bf(w1[k * 256 + n]);
}

// h fp32 -> bf16
__global__ void prep_hbf(const float* __restrict__ h, ushort* __restrict__ hbf) {
    int i = blockIdx.x * 256 + threadIdx.x;
    const float4* src = (const float4*)h + (size_t)i * 2;
    float4 a = src[0], b = src[1];
    union { ushort s[8]; uint4 v; } o;
    o.s[0] = f2bf(a.x); o.s[1] = f2bf(a.y); o.s[2] = f2bf(a.z); o.s[3] = f2bf(a.w);
    o.s[4] = f2bf(b.x); o.s[5] = f2bf(b.y); o.s[6] = f2bf(b.z); o.s[7] = f2bf(b.w);
    ((uint4*)hbf)[i] = o.v;
}

// ================= V0: the real kernel (byte-identical to R6) =============
__global__ __launch_bounds__(BLK, 2)
void decoder(const ushort* __restrict__ hbf, const int2* __restrict__ edges,
             const ushort* __restrict__ w1t, const float* __restrict__ b1,
             const float* __restrict__ w2, const float* __restrict__ b2p,
             float* __restrict__ out) {
    __shared__ ushort xlds[2][MT][264];   // 33.8 KB
    __shared__ float part[2][4][MT];      // 1 KB
    __shared__ int2 eld[MAXJ * MT];       // 4.9 KB

    const int t = threadIdx.x;
    const int w = t >> 6, lane = t & 63, quad = lane >> 4, l15 = lane & 15;
    const int bx = blockIdx.x, gdim = gridDim.x;
    const int J = (NTILES - bx + gdim - 1) / gdim;

    bf16x8 Bf[4][8];
#pragma unroll
    for (int nt = 0; nt < 4; ++nt) {
        int n = w * 64 + nt * 16 + l15;
#pragma unroll
        for (int ks = 0; ks < 8; ++ks)
            Bf[nt][ks] = *(const bf16x8*)(w1t + n * 256 + ks * 32 + quad * 8);
    }
    float b1v[4], w2v[4];
#pragma unroll
    for (int nt = 0; nt < 4; ++nt) {
        int n = w * 64 + nt * 16 + l15;
        b1v[nt] = b1[n];
        w2v[nt] = w2[n];
    }
    const float b2v = b2p[0];

    for (int idx = t; idx < J * MT; idx += BLK)
        eld[idx] = edges[(size_t)(bx + (idx >> 5) * gdim) * MT + (idx & 31)];
    __syncthreads();

    const int sm = t >> 3;
    const int sc = t & 7;

    uint4 s0, s1, s2, s3, d0, d1, d2, d3;

    auto issue = [&](int j) {
        int2 ed = eld[j * MT + sm];
        const uint4* ps = (const uint4*)(hbf + (size_t)ed.x * DIM) + sc * 4;
        const uint4* pd = (const uint4*)(hbf + (size_t)ed.y * DIM) + sc * 4;
        s0 = ps[0]; s1 = ps[1]; s2 = ps[2]; s3 = ps[3];
        d0 = pd[0]; d1 = pd[1]; d2 = pd[2]; d3 = pd[3];
    };
    auto mul8 = [](uint4 a, uint4 b) -> uint4 {
        union U { uint4 v; __hip_bfloat162 h[4]; } ua, ub, o;
        ua.v = a; ub.v = b;
#pragma unroll
        for (int q = 0; q < 4; ++q) o.h[q] = __hmul2(ua.h[q], ub.h[q]);
        return o.v;
    };
    auto had = [&](int buf) {
        uint4* dst = (uint4*)&xlds[buf][sm][sc * 32];
        dst[0] = mul8(s0, d0);
        dst[1] = mul8(s1, d1);
        dst[2] = mul8(s2, d2);
        dst[3] = mul8(s3, d3);
    };
    auto finalize = [&](int j, int par) {
        if (t < MT) {
            float s = b2v;
#pragma unroll
            for (int ww = 0; ww < 4; ++ww) s += part[par][ww][t];
            out[(size_t)(bx + j * gdim) * MT + t] = s;
        }
    };

    issue(0);
    had(0);
    if (J > 1) issue(1);

    for (int j = 0; j < J; ++j) {
        const int par = j & 1;
        barrier_lgkm();
        if (j > 0) finalize(j - 1, par ^ 1);

        f32x4 acc[2][4];
#pragma unroll
        for (int ms = 0; ms < 2; ++ms)
#pragma unroll
            for (int nt = 0; nt < 4; ++nt)
                acc[ms][nt] = (f32x4){0.f, 0.f, 0.f, 0.f};
        const ushort* xb = &xlds[par][0][0];
#pragma unroll
        for (int ks = 0; ks < 8; ++ks) {
            int kb = ks * 32 + quad * 8;
            bf16x8 a0 = *(const bf16x8*)(xb + l15 * 264 + kb);
            bf16x8 a1 = *(const bf16x8*)(xb + (16 + l15) * 264 + kb);
#pragma unroll
            for (int nt = 0; nt < 4; ++nt) {
                acc[0][nt] = __builtin_amdgcn_mfma_f32_16x16x32_bf16(a0, Bf[nt][ks], acc[0][nt], 0, 0, 0);
                acc[1][nt] = __builtin_amdgcn_mfma_f32_16x16x32_bf16(a1, Bf[nt][ks], acc[1][nt], 0, 0, 0);
            }
        }
        float red[2][4];
#pragma unroll
        for (int ms = 0; ms < 2; ++ms)
#pragma unroll
            for (int r = 0; r < 4; ++r) {
                float s = 0.f;
#pragma unroll
                for (int nt = 0; nt < 4; ++nt)
                    s += fmaxf(acc[ms][nt][r] + b1v[nt], 0.f) * w2v[nt];
                red[ms][r] = s;
            }
#pragma unroll
        for (int mask = 1; mask <= 8; mask <<= 1)
#pragma unroll
            for (int ms = 0; ms < 2; ++ms)
#pragma unroll
                for (int r = 0; r < 4; ++r)
                    red[ms][r] += __shfl_xor(red[ms][r], mask);
        if (l15 == 0)
#pragma unroll
            for (int ms = 0; ms < 2; ++ms)
#pragma unroll
                for (int r = 0; r < 4; ++r)
                    part[par][w][ms * 16 + quad * 4 + r] = red[ms][r];

        if (j + 1 < J) had(par ^ 1);
        if (j + 2 < J) issue(j + 2);
    }

    __syncthreads();
    finalize(J - 1, (J - 1) & 1);
}

// ============ V1: staging-only ablation (x3 passes, no output) ============
// MFMA+epilogue behind runtime-false `keep` so Bf/acc register pressure and
// occupancy match V0. Measures S = issue/had/barrier pipeline cost.
__global__ __launch_bounds__(BLK, 2)
void decoder_v1(const ushort* __restrict__ hbf, const int2* __restrict__ edges,
                const ushort* __restrict__ w1t, const float* __restrict__ b1,
                const float* __restrict__ w2, const float* __restrict__ b2p,
                float* __restrict__ out, int keep) {
    __shared__ ushort xlds[2][MT][264];
    __shared__ float part[2][4][MT];
    __shared__ int2 eld[MAXJ * MT];

    const int t = threadIdx.x;
    const int w = t >> 6, lane = t & 63, quad = lane >> 4, l15 = lane & 15;
    const int bx = blockIdx.x, gdim = gridDim.x;
    const int J = (NTILES - bx + gdim - 1) / gdim;

    bf16x8 Bf[4][8];
#pragma unroll
    for (int nt = 0; nt < 4; ++nt) {
        int n = w * 64 + nt * 16 + l15;
#pragma unroll
        for (int ks = 0; ks < 8; ++ks)
            Bf[nt][ks] = *(const bf16x8*)(w1t + n * 256 + ks * 32 + quad * 8);
    }
    float b1v[4], w2v[4];
#pragma unroll
    for (int nt = 0; nt < 4; ++nt) {
        int n = w * 64 + nt * 16 + l15;
        b1v[nt] = b1[n];
        w2v[nt] = w2[n];
    }
    const float b2v = b2p[0];

    for (int idx = t; idx < J * MT; idx += BLK)
        eld[idx] = edges[(size_t)(bx + (idx >> 5) * gdim) * MT + (idx & 31)];
    __syncthreads();

    const int sm = t >> 3;
    const int sc = t & 7;
    uint4 s0, s1, s2, s3, d0, d1, d2, d3;

    auto issue = [&](int j) {
        int2 ed = eld[j * MT + sm];
        const uint4* ps = (const uint4*)(hbf + (size_t)ed.x * DIM) + sc * 4;
        const uint4* pd = (const uint4*)(hbf + (size_t)ed.y * DIM) + sc * 4;
        s0 = ps[0]; s1 = ps[1]; s2 = ps[2]; s3 = ps[3];
        d0 = pd[0]; d1 = pd[1]; d2 = pd[2]; d3 = pd[3];
    };
    auto mul8 = [](uint4 a, uint4 b) -> uint4 {
        union U { uint4 v; __hip_bfloat162 h[4]; } ua, ub, o;
        ua.v = a; ub.v = b;
#pragma unroll
        for (int q = 0; q < 4; ++q) o.h[q] = __hmul2(ua.h[q], ub.h[q]);
        return o.v;
    };
    auto had = [&](int buf) {
        uint4* dst = (uint4*)&xlds[buf][sm][sc * 32];
        dst[0] = mul8(s0, d0);
        dst[1] = mul8(s1, d1);
        dst[2] = mul8(s2, d2);
        dst[3] = mul8(s3, d3);
    };

    for (int p = 0; p < 3; ++p) {
        __syncthreads();              // pass boundary: quiesce buffers
        issue(0);
        had(0);
        if (J > 1) issue(1);
        for (int j = 0; j < J; ++j) {
            const int par = j & 1;
            barrier_lgkm();
            if (keep) {               // never true at runtime; keeps pressure
                f32x4 acc[2][4];
#pragma unroll
                for (int ms = 0; ms < 2; ++ms)
#pragma unroll
                    for (int nt = 0; nt < 4; ++nt)
                        acc[ms][nt] = (f32x4){0.f, 0.f, 0.f, 0.f};
                const ushort* xb = &xlds[par][0][0];
#pragma unroll
                for (int ks = 0; ks < 8; ++ks) {
                    int kb = ks * 32 + quad * 8;
                    bf16x8 a0 = *(const bf16x8*)(xb + l15 * 264 + kb);
                    bf16x8 a1 = *(const bf16x8*)(xb + (16 + l15) * 264 + kb);
#pragma unroll
                    for (int nt = 0; nt < 4; ++nt) {
                        acc[0][nt] = __builtin_amdgcn_mfma_f32_16x16x32_bf16(a0, Bf[nt][ks], acc[0][nt], 0, 0, 0);
                        acc[1][nt] = __builtin_amdgcn_mfma_f32_16x16x32_bf16(a1, Bf[nt][ks], acc[1][nt], 0, 0, 0);
                    }
                }
                float red[2][4];
#pragma unroll
                for (int ms = 0; ms < 2; ++ms)
#pragma unroll
                    for (int r = 0; r < 4; ++r) {
                        float s = 0.f;
#pragma unroll
                        for (int nt = 0; nt < 4; ++nt)
                            s += fmaxf(acc[ms][nt][r] + b1v[nt], 0.f) * w2v[nt];
                        red[ms][r] = s;
                    }
#pragma unroll
                for (int mask = 1; mask <= 8; mask <<= 1)
#pragma unroll
                    for (int ms = 0; ms < 2; ++ms)
#pragma unroll
                        for (int r = 0; r < 4; ++r)
                            red[ms][r] += __shfl_xor(red[ms][r], mask);
                if (l15 == 0)
#pragma unroll
                    for (int ms = 0; ms < 2; ++ms)
#pragma unroll
                        for (int r = 0; r < 4; ++r)
                            part[par][w][ms * 16 + quad * 4 + r] = red[ms][r];
                if (t < MT) {
                    float s = b2v;
#pragma unroll
                    for (int ww = 0; ww < 4; ++ww) s += part[par][ww][t];
                    out[(size_t)(bx + j * gdim) * MT + t] = s;
                }
            }
            if (j + 1 < J) had(par ^ 1);
            if (j + 2 < J) issue(j + 2);
        }
    }
}

// ========= V2: staging + MFMA ablation (x2 passes, epilogue guarded) ======
__global__ __launch_bounds__(BLK, 2)
void decoder_v2(const ushort* __restrict__ hbf, const int2* __restrict__ edges,
                const ushort* __restrict__ w1t, const float* __restrict__ b1,
                const float* __restrict__ w2, const float* __restrict__ b2p,
                float* __restrict__ out, int keep) {
    __shared__ ushort xlds[2][MT][264];
    __shared__ float part[2][4][MT];
    __shared__ int2 eld[MAXJ * MT];

    const int t = threadIdx.x;
    const int w = t >> 6, lane = t & 63, quad = lane >> 4, l15 = lane & 15;
    const int bx = blockIdx.x, gdim = gridDim.x;
    const int J = (NTILES - bx + gdim - 1) / gdim;

    bf16x8 Bf[4][8];
#pragma unroll
    for (int nt = 0; nt < 4; ++nt) {
        int n = w * 64 + nt * 16 + l15;
#pragma unroll
        for (int ks = 0; ks < 8; ++ks)
            Bf[nt][ks] = *(const bf16x8*)(w1t + n * 256 + ks * 32 + quad * 8);
    }
    float b1v[4], w2v[4];
#pragma unroll
    for (int nt = 0; nt < 4; ++nt) {
        int n = w * 64 + nt * 16 + l15;
        b1v[nt] = b1[n];
        w2v[nt] = w2[n];
    }
    const float b2v = b2p[0];

    for (int idx = t; idx < J * MT; idx += BLK)
        eld[idx] = edges[(size_t)(bx + (idx >> 5) * gdim) * MT + (idx & 31)];
    __syncthreads();

    const int sm = t >> 3;
    const int sc = t & 7;
    uint4 s0, s1, s2, s3, d0, d1, d2, d3;

    auto issue = [&](int j) {
        int2 ed = eld[j * MT + sm];
        const uint4* ps = (const uint4*)(hbf + (size_t)ed.x * DIM) + sc * 4;
        const uint4* pd = (const uint4*)(hbf + (size_t)ed.y * DIM) + sc * 4;
        s0 = ps[0]; s1 = ps[1]; s2 = ps[2]; s3 = ps[3];
        d0 = pd[0]; d1 = pd[1]; d2 = pd[2]; d3 = pd[3];
    };
    auto mul8 = [](uint4 a, uint4 b) -> uint4 {
        union U { uint4 v; __hip_bfloat162 h[4]; } ua, ub, o;
        ua.v = a; ub.v = b;
#pragma unroll
        for (int q = 0; q < 4; ++q) o.h[q] = __hmul2(ua.h[q], ub.h[q]);
        return o.v;
    };
    auto had = [&](int buf) {
        uint4* dst = (uint4*)&xlds[buf][sm][sc * 32];
        dst[0] = mul8(s0, d0);
        dst[1] = mul8(s1, d1);
        dst[2] = mul8(s2, d2);
        dst[3] = mul8(s3, d3);
    };

    for (int p = 0; p < 2; ++p) {
        __syncthreads();
        issue(0);
        had(0);
        if (J > 1) issue(1);
        for (int j = 0; j < J; ++j) {
            const int par = j & 1;
            barrier_lgkm();

            f32x4 acc[2][4];
#pragma unroll
            for (int ms = 0; ms < 2; ++ms)
#pragma unroll
                for (int nt = 0; nt < 4; ++nt)
                    acc[ms][nt] = (f32x4){0.f, 0.f, 0.f, 0.f};
            const ushort* xb = &xlds[par][0][0];
#pragma unroll
            for (int ks = 0; ks < 8; ++ks) {
                int kb = ks * 32 + quad * 8;
                bf16x8 a0 = *(const bf16x8*)(xb + l15 * 264 + kb);
                bf16x8 a1 = *(const bf16x8*)(xb + (16 + l15) * 264 + kb);
#pragma unroll
                for (int nt = 0; nt < 4; ++nt) {
                    acc[0][nt] = __builtin_amdgcn_mfma_f32_16x16x32_bf16(a0, Bf[nt][ks], acc[0][nt], 0, 0, 0);
                    acc[1][nt] = __builtin_amdgcn_mfma_f32_16x16x32_bf16(a1, Bf[nt][ks], acc[1][nt], 0, 0, 0);
                }
            }
            // keep all 8 MFMA chains live without the epilogue (rule #17)
            asm volatile("" ::
                "v"(acc[0][0][0]), "v"(acc[0][1][0]), "v"(acc[0][2][0]), "v"(acc[0][3][0]),
                "v"(acc[1][0][0]), "v"(acc[1][1][0]), "v"(acc[1][2][0]), "v"(acc[1][3][0]));

            if (keep) {               // never true at runtime
                float red[2][4];
#pragma unroll
                for (int ms = 0; ms < 2; ++ms)
#pragma unroll
                    for (int r = 0; r < 4; ++r) {
                        float s = 0.f;
#pragma unroll
                        for (int nt = 0; nt < 4; ++nt)
                            s += fmaxf(acc[ms][nt][r] + b1v[nt], 0.f) * w2v[nt];
                        red[ms][r] = s;
                    }
#pragma unroll
                for (int mask = 1; mask <= 8; mask <<= 1)
#pragma unroll
                    for (int ms = 0; ms < 2; ++ms)
#pragma unroll
                        for (int r = 0; r < 4; ++r)
                            red[ms][r] += __shfl_xor(red[ms][r], mask);
                if (l15 == 0)
#pragma unroll
                    for (int ms = 0; ms < 2; ++ms)
#pragma unroll
                        for (int r = 0; r < 4; ++r)
                            part[par][w][ms * 16 + quad * 4 + r] = red[ms][r];
                if (t < MT) {
                    float s = b2v;
#pragma unroll
                    for (int ww = 0; ww < 4; ++ww) s += part[par][ww][t];
                    out[(size_t)(bx + j * gdim) * MT + t] = s;
                }
            }

            if (j + 1 < J) had(par ^ 1);
            if (j + 2 < J) issue(j + 2);
        }
    }
}

// fp32-gather fallback (only if ws too small for hbf; not expected to run)
__global__ __launch_bounds__(512, 4)
void decoder_f32(const float* __restrict__ h, const int2* __restrict__ edges,
                 const ushort* __restrict__ w1t, const float* __restrict__ b1,
                 const float* __restrict__ w2, const float* __restrict__ b2p,
                 float* __restrict__ out) {
    __shared__ ushort xlds[MT][264];
    __shared__ float part[8][MT];
    const int t = threadIdx.x;
    const int w = t >> 6, lane = t & 63, quad = lane >> 4, l15 = lane & 15;
    bf16x8 Bf[2][8];
#pragma unroll
    for (int nt = 0; nt < 2; ++nt)
#pragma unroll
        for (int ks = 0; ks < 8; ++ks)
            Bf[nt][ks] = *(const bf16x8*)(w1t + (w * 32 + nt * 16 + l15) * 256 + ks * 32 + quad * 8);
    float b1v[2], w2v[2];
#pragma unroll
    for (int nt = 0; nt < 2; ++nt) {
        b1v[nt] = b1[w * 32 + nt * 16 + l15];
        w2v[nt] = w2[w * 32 + nt * 16 + l15];
    }
    const float b2v = b2p[0];
    const int sm = t >> 4, sc = t & 15;
    for (int mb = blockIdx.x; mb < NTILES; mb += gridDim.x) {
        int2 ed = edges[mb * MT + sm];
        const float4* ps = (const float4*)(h + (size_t)ed.x * DIM) + sc * 4;
        const float4* pd = (const float4*)(h + (size_t)ed.y * DIM) + sc * 4;
        union { ushort s[16]; uint4 v[2]; } o;
#pragma unroll
        for (int jj = 0; jj < 4; ++jj) {
            float4 a = ps[jj], b = pd[jj];
            o.s[4 * jj + 0] = f2bf(a.x * b.x); o.s[4 * jj + 1] = f2bf(a.y * b.y);
            o.s[4 * jj + 2] = f2bf(a.z * b.z); o.s[4 * jj + 3] = f2bf(a.w * b.w);
        }
        uint4* dst = (uint4*)&xlds[sm][sc * 16];
        dst[0] = o.v[0]; dst[1] = o.v[1];
        __syncthreads();
        f32x4 acc[2][2];
#pragma unroll
        for (int ms = 0; ms < 2; ++ms)
#pragma unroll
            for (int nt = 0; nt < 2; ++nt) acc[ms][nt] = (f32x4){0.f,0.f,0.f,0.f};
#pragma unroll
        for (int ks = 0; ks < 8; ++ks) {
            int kb = ks * 32 + quad * 8;
            bf16x8 a0 = *(const bf16x8*)&xlds[l15][kb];
            bf16x8 a1 = *(const bf16x8*)&xlds[16 + l15][kb];
#pragma unroll
            for (int nt = 0; nt < 2; ++nt) {
                acc[0][nt] = __builtin_amdgcn_mfma_f32_16x16x32_bf16(a0, Bf[nt][ks], acc[0][nt], 0, 0, 0);
                acc[1][nt] = __builtin_amdgcn_mfma_f32_16x16x32_bf16(a1, Bf[nt][ks], acc[1][nt], 0, 0, 0);
            }
        }
        float red[2][4];
#pragma unroll
        for (int ms = 0; ms < 2; ++ms)
#pragma unroll
            for (int r = 0; r < 4; ++r) {
                float s = 0.f;
#pragma unroll
                for (int nt = 0; nt < 2; ++nt)
                    s += fmaxf(acc[ms][nt][r] + b1v[nt], 0.f) * w2v[nt];
                red[ms][r] = s;
            }
#pragma unroll
        for (int mask = 1; mask <= 8; mask <<= 1)
#pragma unroll
            for (int ms = 0; ms < 2; ++ms)
#pragma unroll
                for (int r = 0; r < 4; ++r)
                    red[ms][r] += __shfl_xor(red[ms][r], mask);
        if (l15 == 0)
#pragma unroll
            for (int ms = 0; ms < 2; ++ms)
#pragma unroll
                for (int r = 0; r < 4; ++r)
                    part[w][ms * 16 + quad * 4 + r] = red[ms][r];
        __syncthreads();
        if (t < MT) {
            float s = b2v;
#pragma unroll
            for (int ww = 0; ww < 8; ++ww) s += part[ww][t];
            out[mb * MT + t] = s;
        }
    }
}

extern "C" void kernel_launch(void* const* d_in, const int* in_sizes, int n_in,
                              void* d_out, int out_size, void* d_ws, size_t ws_size,
                              hipStream_t stream) {
    const float* h     = (const float*)d_in[0];
    const int2*  edges = (const int2*)d_in[1];
    const float* W1    = (const float*)d_in[2];
    const float* b1    = (const float*)d_in[3];
    const float* W2    = (const float*)d_in[4];
    const float* b2    = (const float*)d_in[5];
    float* out = (float*)d_out;

    ushort* w1t = (ushort*)d_ws;                     // 128 KB
    ushort* hbf = (ushort*)((char*)d_ws + 131072);   // 51.2 MB

    prep_w1t<<<256, 256, 0, stream>>>(W1, w1t);
    if (ws_size >= 131072 + (size_t)25600000 * 2) {
        prep_hbf<<<12500, 256, 0, stream>>>(h, hbf);
        // V0 first: real output (v1/v2 never touch `out` with keep=0)
        decoder<<<GRID_MAIN, BLK, 0, stream>>>(hbf, edges, w1t, b1, W2, b2, out);
        decoder_v1<<<GRID_MAIN, BLK, 0, stream>>>(hbf, edges, w1t, b1, W2, b2, out, 0);
        decoder_v2<<<GRID_MAIN, BLK, 0, stream>>>(hbf, edges, w1t, b1, W2, b2, out, 0);
    } else {
        decoder_f32<<<512, 512, 0, stream>>>(h, edges, w1t, b1, W2, b2, out);
    }
}

// Round 8
// 227.725 us; speedup vs baseline: 1.8750x; 1.8750x over previous
//
#include <hip/hip_runtime.h>
#include <hip/hip_bf16.h>

// MLPDecoder: scores[e] = relu((h[src]*h[dst]) @ W1 + b1) @ W2 + b2
// E=300000, D=256. bf16 MFMA, 1-barrier/iter pipeline.
// R1: latency theory (Occ 34.5%) -> grid bump: NEUTRAL.
// R2 FAILED: lb(512,8) clamped VGPR->32, spilled (WRITE 142MB, 241us).
// R3 NEUTRAL: GRID=1024+lb(512,4): 78us (VGPR was binding then).
// R4 NEUTRAL: no-vmcnt-drain barrier + MFMA-first order: 77us.
// R5 FAILED: 64-col waves lb(256,4) -> VGPR clamp -> spill, 207us.
// R6 WIN: 64-col waves + lb(256,2): 64.2us. VGPR 120, MfmaUtil 25%.
// R7 ABLATION: v1 staging-only = 41.4us/pass (65% of V0); v2 absent from
// top-5 => MFMA adds <21us. v1 fetch BW = 138.5MB/41.4us = 3.35 TB/s ==
// the scattered-gather L2-miss path ceiling (random 512B rows in 51.2MB
// hbf, ~46% L2 miss). STAGING IS FETCH-PATH-BOUND at ~41us floor.
// V0's extra 23us = non-overlapped compute: 2 blocks/CU in near-lockstep.
// R8: GRID 512->1024 (4 blocks/CU now that VGPR=120<=128 and LDS
// 37.4KBx4=149.5KB fit — unlike R3 where VGPR bound at 2). MAXJ 19->10.
// Pred: Occ 21->~40%, dur 64->~50us. If <=45: fetch wall -> bucketing
// next. If ~64: overlap theory wrong -> bucketing immediately.

#define E_EDGES 300000
#define DIM 256
#define MT 32                    // edges per block-iteration
#define NTILES (E_EDGES / MT)    // 9375
#define BLK 256                  // 4 waves; each wave owns 64 N-cols
#define GRID_MAIN 1024           // 4 blocks/CU
#define MAXJ 10                  // ceil(9375/1024)

typedef short bf16x8 __attribute__((ext_vector_type(8)));
typedef float f32x4 __attribute__((ext_vector_type(4)));

__device__ __forceinline__ ushort f2bf(float f) {
    union { float f; unsigned u; } v; v.f = f;
    unsigned r = v.u + 0x7FFFu + ((v.u >> 16) & 1u);  // RNE
    return (ushort)(r >> 16);
}

// Barrier that does NOT drain vmcnt (LDS producers covered by lgkmcnt(0)).
__device__ __forceinline__ void barrier_lgkm() {
    asm volatile("s_waitcnt lgkmcnt(0)" ::: "memory");
    asm volatile("s_barrier" ::: "memory");
}

// W1 fp32 [K=256][N=256] -> W1^T bf16 [N][K]
__global__ void prep_w1t(const float* __restrict__ w1, ushort* __restrict__ w1t) {
    int idx = blockIdx.x * 256 + threadIdx.x;
    int k = idx >> 8, n = idx & 255;
    w1t[n * 256 + k] = f2bf(w1[k * 256 + n]);
}

// h fp32 -> bf16
__global__ void prep_hbf(const float* __restrict__ h, ushort* __restrict__ hbf) {
    int i = blockIdx.x * 256 + threadIdx.x;
    const float4* src = (const float4*)h + (size_t)i * 2;
    float4 a = src[0], b = src[1];
    union { ushort s[8]; uint4 v; } o;
    o.s[0] = f2bf(a.x); o.s[1] = f2bf(a.y); o.s[2] = f2bf(a.z); o.s[3] = f2bf(a.w);
    o.s[4] = f2bf(b.x); o.s[5] = f2bf(b.y); o.s[6] = f2bf(b.z); o.s[7] = f2bf(b.w);
    ((uint4*)hbf)[i] = o.v;
}

__global__ __launch_bounds__(BLK, 2)
void decoder(const ushort* __restrict__ hbf, const int2* __restrict__ edges,
             const ushort* __restrict__ w1t, const float* __restrict__ b1,
             const float* __restrict__ w2, const float* __restrict__ b2p,
             float* __restrict__ out) {
    __shared__ ushort xlds[2][MT][264];   // 33.8 KB
    __shared__ float part[2][4][MT];      // 1 KB
    __shared__ int2 eld[MAXJ * MT];       // 2.6 KB

    const int t = threadIdx.x;
    const int w = t >> 6, lane = t & 63, quad = lane >> 4, l15 = lane & 15;
    const int bx = blockIdx.x, gdim = gridDim.x;
    const int J = (NTILES - bx + gdim - 1) / gdim;   // 9 or 10 tiles

    bf16x8 Bf[4][8];   // wave w owns N cols [64w, 64w+64)
#pragma unroll
    for (int nt = 0; nt < 4; ++nt) {
        int n = w * 64 + nt * 16 + l15;
#pragma unroll
        for (int ks = 0; ks < 8; ++ks)
            Bf[nt][ks] = *(const bf16x8*)(w1t + n * 256 + ks * 32 + quad * 8);
    }
    float b1v[4], w2v[4];
#pragma unroll
    for (int nt = 0; nt < 4; ++nt) {
        int n = w * 64 + nt * 16 + l15;
        b1v[nt] = b1[n];
        w2v[nt] = w2[n];
    }
    const float b2v = b2p[0];

    for (int idx = t; idx < J * MT; idx += BLK)
        eld[idx] = edges[(size_t)(bx + (idx >> 5) * gdim) * MT + (idx & 31)];
    __syncthreads();

    const int sm = t >> 3;     // edge row in tile 0..31
    const int sc = t & 7;      // 64B chunk in row

    uint4 s0, s1, s2, s3, d0, d1, d2, d3;

    auto issue = [&](int j) {
        int2 ed = eld[j * MT + sm];
        const uint4* ps = (const uint4*)(hbf + (size_t)ed.x * DIM) + sc * 4;
        const uint4* pd = (const uint4*)(hbf + (size_t)ed.y * DIM) + sc * 4;
        s0 = ps[0]; s1 = ps[1]; s2 = ps[2]; s3 = ps[3];
        d0 = pd[0]; d1 = pd[1]; d2 = pd[2]; d3 = pd[3];
    };
    auto mul8 = [](uint4 a, uint4 b) -> uint4 {
        union U { uint4 v; __hip_bfloat162 h[4]; } ua, ub, o;
        ua.v = a; ub.v = b;
#pragma unroll
        for (int q = 0; q < 4; ++q) o.h[q] = __hmul2(ua.h[q], ub.h[q]);
        return o.v;
    };
    auto had = [&](int buf) {
        uint4* dst = (uint4*)&xlds[buf][sm][sc * 32];
        dst[0] = mul8(s0, d0);
        dst[1] = mul8(s1, d1);
        dst[2] = mul8(s2, d2);
        dst[3] = mul8(s3, d3);
    };
    auto finalize = [&](int j, int par) {
        if (t < MT) {
            float s = b2v;
#pragma unroll
            for (int ww = 0; ww < 4; ++ww) s += part[par][ww][t];
            out[(size_t)(bx + j * gdim) * MT + t] = s;
        }
    };

    issue(0);
    had(0);
    if (J > 1) issue(1);

    for (int j = 0; j < J; ++j) {
        const int par = j & 1;
        barrier_lgkm();
        if (j > 0) finalize(j - 1, par ^ 1);

        f32x4 acc[2][4];
#pragma unroll
        for (int ms = 0; ms < 2; ++ms)
#pragma unroll
            for (int nt = 0; nt < 4; ++nt)
                acc[ms][nt] = (f32x4){0.f, 0.f, 0.f, 0.f};
        const ushort* xb = &xlds[par][0][0];
#pragma unroll
        for (int ks = 0; ks < 8; ++ks) {
            int kb = ks * 32 + quad * 8;
            bf16x8 a0 = *(const bf16x8*)(xb + l15 * 264 + kb);
            bf16x8 a1 = *(const bf16x8*)(xb + (16 + l15) * 264 + kb);
#pragma unroll
            for (int nt = 0; nt < 4; ++nt) {
                acc[0][nt] = __builtin_amdgcn_mfma_f32_16x16x32_bf16(a0, Bf[nt][ks], acc[0][nt], 0, 0, 0);
                acc[1][nt] = __builtin_amdgcn_mfma_f32_16x16x32_bf16(a1, Bf[nt][ks], acc[1][nt], 0, 0, 0);
            }
        }
        // epilogue: relu(hid+b1).w2, butterfly over 16 n-lanes
        float red[2][4];
#pragma unroll
        for (int ms = 0; ms < 2; ++ms)
#pragma unroll
            for (int r = 0; r < 4; ++r) {
                float s = 0.f;
#pragma unroll
                for (int nt = 0; nt < 4; ++nt)
                    s += fmaxf(acc[ms][nt][r] + b1v[nt], 0.f) * w2v[nt];
                red[ms][r] = s;
            }
#pragma unroll
        for (int mask = 1; mask <= 8; mask <<= 1)
#pragma unroll
            for (int ms = 0; ms < 2; ++ms)
#pragma unroll
                for (int r = 0; r < 4; ++r)
                    red[ms][r] += __shfl_xor(red[ms][r], mask);
        if (l15 == 0)
#pragma unroll
            for (int ms = 0; ms < 2; ++ms)
#pragma unroll
                for (int r = 0; r < 4; ++r)
                    part[par][w][ms * 16 + quad * 4 + r] = red[ms][r];

        if (j + 1 < J) had(par ^ 1);
        if (j + 2 < J) issue(j + 2);
    }

    __syncthreads();
    finalize(J - 1, (J - 1) & 1);
}

// fp32-gather fallback (only if ws too small for hbf; not expected to run)
__global__ __launch_bounds__(512, 4)
void decoder_f32(const float* __restrict__ h, const int2* __restrict__ edges,
                 const ushort* __restrict__ w1t, const float* __restrict__ b1,
                 const float* __restrict__ w2, const float* __restrict__ b2p,
                 float* __restrict__ out) {
    __shared__ ushort xlds[MT][264];
    __shared__ float part[8][MT];
    const int t = threadIdx.x;
    const int w = t >> 6, lane = t & 63, quad = lane >> 4, l15 = lane & 15;
    bf16x8 Bf[2][8];
#pragma unroll
    for (int nt = 0; nt < 2; ++nt)
#pragma unroll
        for (int ks = 0; ks < 8; ++ks)
            Bf[nt][ks] = *(const bf16x8*)(w1t + (w * 32 + nt * 16 + l15) * 256 + ks * 32 + quad * 8);
    float b1v[2], w2v[2];
#pragma unroll
    for (int nt = 0; nt < 2; ++nt) {
        b1v[nt] = b1[w * 32 + nt * 16 + l15];
        w2v[nt] = w2[w * 32 + nt * 16 + l15];
    }
    const float b2v = b2p[0];
    const int sm = t >> 4, sc = t & 15;
    for (int mb = blockIdx.x; mb < NTILES; mb += gridDim.x) {
        int2 ed = edges[mb * MT + sm];
        const float4* ps = (const float4*)(h + (size_t)ed.x * DIM) + sc * 4;
        const float4* pd = (const float4*)(h + (size_t)ed.y * DIM) + sc * 4;
        union { ushort s[16]; uint4 v[2]; } o;
#pragma unroll
        for (int jj = 0; jj < 4; ++jj) {
            float4 a = ps[jj], b = pd[jj];
            o.s[4 * jj + 0] = f2bf(a.x * b.x); o.s[4 * jj + 1] = f2bf(a.y * b.y);
            o.s[4 * jj + 2] = f2bf(a.z * b.z); o.s[4 * jj + 3] = f2bf(a.w * b.w);
        }
        uint4* dst = (uint4*)&xlds[sm][sc * 16];
        dst[0] = o.v[0]; dst[1] = o.v[1];
        __syncthreads();
        f32x4 acc[2][2];
#pragma unroll
        for (int ms = 0; ms < 2; ++ms)
#pragma unroll
            for (int nt = 0; nt < 2; ++nt) acc[ms][nt] = (f32x4){0.f,0.f,0.f,0.f};
#pragma unroll
        for (int ks = 0; ks < 8; ++ks) {
            int kb = ks * 32 + quad * 8;
            bf16x8 a0 = *(const bf16x8*)&xlds[l15][kb];
            bf16x8 a1 = *(const bf16x8*)&xlds[16 + l15][kb];
#pragma unroll
            for (int nt = 0; nt < 2; ++nt) {
                acc[0][nt] = __builtin_amdgcn_mfma_f32_16x16x32_bf16(a0, Bf[nt][ks], acc[0][nt], 0, 0, 0);
                acc[1][nt] = __builtin_amdgcn_mfma_f32_16x16x32_bf16(a1, Bf[nt][ks], acc[1][nt], 0, 0, 0);
            }
        }
        float red[2][4];
#pragma unroll
        for (int ms = 0; ms < 2; ++ms)
#pragma unroll
            for (int r = 0; r < 4; ++r) {
                float s = 0.f;
#pragma unroll
                for (int nt = 0; nt < 2; ++nt)
                    s += fmaxf(acc[ms][nt][r] + b1v[nt], 0.f) * w2v[nt];
                red[ms][r] = s;
            }
#pragma unroll
        for (int mask = 1; mask <= 8; mask <<= 1)
#pragma unroll
            for (int ms = 0; ms < 2; ++ms)
#pragma unroll
                for (int r = 0; r < 4; ++r)
                    red[ms][r] += __shfl_xor(red[ms][r], mask);
        if (l15 == 0)
#pragma unroll
            for (int ms = 0; ms < 2; ++ms)
#pragma unroll
                for (int r = 0; r < 4; ++r)
                    part[w][ms * 16 + quad * 4 + r] = red[ms][r];
        __syncthreads();
        if (t < MT) {
            float s = b2v;
#pragma unroll
            for (int ww = 0; ww < 8; ++ww) s += part[ww][t];
            out[mb * MT + t] = s;
        }
    }
}

extern "C" void kernel_launch(void* const* d_in, const int* in_sizes, int n_in,
                              void* d_out, int out_size, void* d_ws, size_t ws_size,
                              hipStream_t stream) {
    const float* h     = (const float*)d_in[0];
    const int2*  edges = (const int2*)d_in[1];
    const float* W1    = (const float*)d_in[2];
    const float* b1    = (const float*)d_in[3];
    const float* W2    = (const float*)d_in[4];
    const float* b2    = (const float*)d_in[5];
    float* out = (float*)d_out;

    ushort* w1t = (ushort*)d_ws;                     // 128 KB
    ushort* hbf = (ushort*)((char*)d_ws + 131072);   // 51.2 MB

    prep_w1t<<<256, 256, 0, stream>>>(W1, w1t);
    if (ws_size >= 131072 + (size_t)25600000 * 2) {
        prep_hbf<<<12500, 256, 0, stream>>>(h, hbf);
        decoder<<<GRID_MAIN, BLK, 0, stream>>>(hbf, edges, w1t, b1, W2, b2, out);
    } else {
        decoder_f32<<<512, 512, 0, stream>>>(h, edges, w1t, b1, W2, b2, out);
    }
}